// Round 1
// baseline (1193.626 us; speedup 1.0000x reference)
//
#include <hip/hip_runtime.h>
#include <hip/hip_bf16.h>
#include <cstdint>

// Problem constants (from reference)
constexpr int B_ = 4;
constexpr int S_ = 2048;
constexpr int D_ = 512;
constexpr int H_ = 8;
constexpr int DK_ = 64;
constexpr int M_ = B_ * S_;  // 8192 rows for projections

// ---------------------------------------------------------------------------
// GEMM_NT: C[i][j] = sum_d A[i][d] * W[j][d]
// A: [M,512] row-major, W: [512,512] row-major, C: [M,512]
// 64x64 tile, BK=32, 256 threads, 4x4 microtile.
// ---------------------------------------------------------------------------
__global__ __launch_bounds__(256) void gemm_nt(const float* __restrict__ A,
                                               const float* __restrict__ W,
                                               float* __restrict__ C) {
    constexpr int K = 512;
    __shared__ float As[32][65];  // [k][m], +1 pad
    __shared__ float Ws[32][65];  // [k][n]
    const int tid = threadIdx.x;
    const int tx = tid & 15;       // n-group
    const int ty = tid >> 4;       // m-group
    const int bm = blockIdx.x * 64;
    const int bn = blockIdx.y * 64;

    float acc[4][4] = {};

    for (int k0 = 0; k0 < K; k0 += 32) {
#pragma unroll
        for (int l = 0; l < 2; ++l) {
            int idx = tid + l * 256;       // 0..511
            int r = idx >> 3;              // 0..63
            int c = (idx & 7) << 2;        // 0,4,...,28
            float4 av = *reinterpret_cast<const float4*>(&A[(size_t)(bm + r) * K + k0 + c]);
            As[c + 0][r] = av.x; As[c + 1][r] = av.y;
            As[c + 2][r] = av.z; As[c + 3][r] = av.w;
            float4 wv = *reinterpret_cast<const float4*>(&W[(size_t)(bn + r) * K + k0 + c]);
            Ws[c + 0][r] = wv.x; Ws[c + 1][r] = wv.y;
            Ws[c + 2][r] = wv.z; Ws[c + 3][r] = wv.w;
        }
        __syncthreads();
#pragma unroll
        for (int kk = 0; kk < 32; ++kk) {
            float a[4], w[4];
#pragma unroll
            for (int i = 0; i < 4; ++i) a[i] = As[kk][ty * 4 + i];
#pragma unroll
            for (int j = 0; j < 4; ++j) w[j] = Ws[kk][tx * 4 + j];
#pragma unroll
            for (int i = 0; i < 4; ++i)
#pragma unroll
                for (int j = 0; j < 4; ++j) acc[i][j] += a[i] * w[j];
        }
        __syncthreads();
    }

#pragma unroll
    for (int i = 0; i < 4; ++i) {
        int row = bm + ty * 4 + i;
        float4 o = make_float4(acc[i][0], acc[i][1], acc[i][2], acc[i][3]);
        *reinterpret_cast<float4*>(&C[(size_t)row * 512 + bn + tx * 4]) = o;
    }
}

// ---------------------------------------------------------------------------
// Scores: P[b,h,i,j] = mask ? -1e9 : dot64(Q[b,i,h*64:],K[b,j,h*64:]) / 8
// grid: (S/64 j-tiles, S/64 i-tiles, B*H). Writes scores into d_out weights region.
// ---------------------------------------------------------------------------
__global__ __launch_bounds__(256) void scores_kernel(const float* __restrict__ Q,
                                                     const float* __restrict__ Km,
                                                     const int* __restrict__ mask,
                                                     float* __restrict__ P) {
    __shared__ float Qs[64][65];  // [d][i]
    __shared__ float Ks[64][65];  // [d][j]
    const int bh = blockIdx.z;
    const int b = bh >> 3;   // / H_
    const int h = bh & 7;    // % H_
    const int i0 = blockIdx.y * 64;
    const int j0 = blockIdx.x * 64;
    const int tid = threadIdx.x;
    const int tx = tid & 15;
    const int ty = tid >> 4;

    const float* Qbase = Q + (size_t)(b * S_ + i0) * D_ + h * DK_;
    const float* Kbase = Km + (size_t)(b * S_ + j0) * D_ + h * DK_;

#pragma unroll
    for (int l = 0; l < 4; ++l) {
        int idx = tid + l * 256;       // 0..1023
        int r = idx >> 4;              // 0..63
        int c = (idx & 15) << 2;       // 0..60
        float4 qv = *reinterpret_cast<const float4*>(&Qbase[(size_t)r * D_ + c]);
        Qs[c + 0][r] = qv.x; Qs[c + 1][r] = qv.y;
        Qs[c + 2][r] = qv.z; Qs[c + 3][r] = qv.w;
        float4 kv = *reinterpret_cast<const float4*>(&Kbase[(size_t)r * D_ + c]);
        Ks[c + 0][r] = kv.x; Ks[c + 1][r] = kv.y;
        Ks[c + 2][r] = kv.z; Ks[c + 3][r] = kv.w;
    }
    __syncthreads();

    float acc[4][4] = {};
#pragma unroll 16
    for (int kk = 0; kk < 64; ++kk) {
        float a[4], w[4];
#pragma unroll
        for (int i = 0; i < 4; ++i) a[i] = Qs[kk][ty * 4 + i];
#pragma unroll
        for (int j = 0; j < 4; ++j) w[j] = Ks[kk][tx * 4 + j];
#pragma unroll
        for (int i = 0; i < 4; ++i)
#pragma unroll
            for (int j = 0; j < 4; ++j) acc[i][j] += a[i] * w[j];
    }

    const float scale = 0.125f;  // 1/sqrt(64)
#pragma unroll
    for (int i = 0; i < 4; ++i) {
        int gi = i0 + ty * 4 + i;
        const int* mrow = mask + (size_t)b * S_ * S_ + (size_t)gi * S_ + j0;
        float* prow = P + ((size_t)bh * S_ + gi) * S_ + j0;
        float4 o;
        int gj = tx * 4;
        o.x = mrow[gj + 0] ? -1e9f : acc[i][0] * scale;
        o.y = mrow[gj + 1] ? -1e9f : acc[i][1] * scale;
        o.z = mrow[gj + 2] ? -1e9f : acc[i][2] * scale;
        o.w = mrow[gj + 3] ? -1e9f : acc[i][3] * scale;
        *reinterpret_cast<float4*>(&prow[gj]) = o;
    }
}

// ---------------------------------------------------------------------------
// Softmax (in-place) over last dim of P rows. One block (256 thr) per row of 2048.
// ---------------------------------------------------------------------------
__global__ __launch_bounds__(256) void softmax_kernel(float* __restrict__ P) {
    const int tid = threadIdx.x;
    float* p = P + (size_t)blockIdx.x * S_;

    float4 v0 = *reinterpret_cast<const float4*>(&p[tid * 8]);
    float4 v1 = *reinterpret_cast<const float4*>(&p[tid * 8 + 4]);

    float mx = fmaxf(fmaxf(fmaxf(v0.x, v0.y), fmaxf(v0.z, v0.w)),
                     fmaxf(fmaxf(v1.x, v1.y), fmaxf(v1.z, v1.w)));
#pragma unroll
    for (int off = 32; off > 0; off >>= 1) mx = fmaxf(mx, __shfl_xor(mx, off, 64));

    __shared__ float redmax[4];
    __shared__ float redsum[4];
    const int wid = tid >> 6;
    if ((tid & 63) == 0) redmax[wid] = mx;
    __syncthreads();
    mx = fmaxf(fmaxf(redmax[0], redmax[1]), fmaxf(redmax[2], redmax[3]));

    float e[8];
    e[0] = __expf(v0.x - mx); e[1] = __expf(v0.y - mx);
    e[2] = __expf(v0.z - mx); e[3] = __expf(v0.w - mx);
    e[4] = __expf(v1.x - mx); e[5] = __expf(v1.y - mx);
    e[6] = __expf(v1.z - mx); e[7] = __expf(v1.w - mx);
    float sum = ((e[0] + e[1]) + (e[2] + e[3])) + ((e[4] + e[5]) + (e[6] + e[7]));
#pragma unroll
    for (int off = 32; off > 0; off >>= 1) sum += __shfl_xor(sum, off, 64);
    if ((tid & 63) == 0) redsum[wid] = sum;
    __syncthreads();
    sum = (redsum[0] + redsum[1]) + (redsum[2] + redsum[3]);

    const float inv = 1.0f / sum;
    float4 o0 = make_float4(e[0] * inv, e[1] * inv, e[2] * inv, e[3] * inv);
    float4 o1 = make_float4(e[4] * inv, e[5] * inv, e[6] * inv, e[7] * inv);
    *reinterpret_cast<float4*>(&p[tid * 8]) = o0;
    *reinterpret_cast<float4*>(&p[tid * 8 + 4]) = o1;
}

// ---------------------------------------------------------------------------
// PV: Attn[b,i,h*64+d] = sum_j P[b,h,i,j] * V[b,j,h*64+d]
// grid: (S/64 i-tiles, B*H). 64(i) x 64(d) tile, BK=32 over j.
// ---------------------------------------------------------------------------
__global__ __launch_bounds__(256) void pv_kernel(const float* __restrict__ P,
                                                 const float* __restrict__ V,
                                                 float* __restrict__ Attn) {
    __shared__ float Ps[32][65];  // [j][i]
    __shared__ float Vs[32][65];  // [j][d]
    const int bh = blockIdx.y;
    const int b = bh >> 3;
    const int h = bh & 7;
    const int i0 = blockIdx.x * 64;
    const int tid = threadIdx.x;
    const int tx = tid & 15;   // d-group
    const int ty = tid >> 4;   // i-group

    const float* Pbase = P + ((size_t)bh * S_ + i0) * S_;    // + i*S + j
    const float* Vbase = V + (size_t)b * S_ * D_ + h * DK_;  // + j*D + d

    float acc[4][4] = {};

    for (int k0 = 0; k0 < S_; k0 += 32) {
#pragma unroll
        for (int l = 0; l < 2; ++l) {
            int idx = tid + l * 256;   // 0..511
            // P tile: 64 rows (i) x 32 cols (j)
            int pr = idx >> 3;             // 0..63
            int pc = (idx & 7) << 2;       // 0..28
            float4 pv = *reinterpret_cast<const float4*>(&Pbase[(size_t)pr * S_ + k0 + pc]);
            Ps[pc + 0][pr] = pv.x; Ps[pc + 1][pr] = pv.y;
            Ps[pc + 2][pr] = pv.z; Ps[pc + 3][pr] = pv.w;
            // V tile: 32 rows (j) x 64 cols (d)
            int vr = idx >> 4;             // 0..31
            int vc = (idx & 15) << 2;      // 0..60
            float4 vv = *reinterpret_cast<const float4*>(&Vbase[(size_t)(k0 + vr) * D_ + vc]);
            Vs[vr][vc + 0] = vv.x; Vs[vr][vc + 1] = vv.y;
            Vs[vr][vc + 2] = vv.z; Vs[vr][vc + 3] = vv.w;
        }
        __syncthreads();
#pragma unroll
        for (int kk = 0; kk < 32; ++kk) {
            float a[4], w[4];
#pragma unroll
            for (int i = 0; i < 4; ++i) a[i] = Ps[kk][ty * 4 + i];
#pragma unroll
            for (int j = 0; j < 4; ++j) w[j] = Vs[kk][tx * 4 + j];
#pragma unroll
            for (int i = 0; i < 4; ++i)
#pragma unroll
                for (int j = 0; j < 4; ++j) acc[i][j] += a[i] * w[j];
        }
        __syncthreads();
    }

#pragma unroll
    for (int i = 0; i < 4; ++i) {
        int gi = i0 + ty * 4 + i;
        float4 o = make_float4(acc[i][0], acc[i][1], acc[i][2], acc[i][3]);
        *reinterpret_cast<float4*>(&Attn[(size_t)(b * S_ + gi) * D_ + h * DK_ + tx * 4]) = o;
    }
}

// ---------------------------------------------------------------------------
extern "C" void kernel_launch(void* const* d_in, const int* in_sizes, int n_in,
                              void* d_out, int out_size, void* d_ws, size_t ws_size,
                              hipStream_t stream) {
    const float* q   = (const float*)d_in[0];
    const float* k   = (const float*)d_in[1];
    const float* v   = (const float*)d_in[2];
    const int*   msk = (const int*)d_in[3];
    const float* w_q = (const float*)d_in[4];
    const float* w_k = (const float*)d_in[5];
    const float* w_v = (const float*)d_in[6];
    const float* w_o = (const float*)d_in[7];

    float* out = (float*)d_out;                       // [B,S,D]
    float* P   = out + (size_t)B_ * S_ * D_;          // [B,H,S,S] attention weights

    float* ws = (float*)d_ws;
    float* Q  = ws;                                   // [B,S,D]
    float* K  = Q + (size_t)M_ * D_;                  // [B,S,D]
    float* V  = K + (size_t)M_ * D_;                  // [B,S,D]
    float* A  = V + (size_t)M_ * D_;                  // [B,S,D] attn (pre w_o)

    dim3 blk(256);
    dim3 gproj(M_ / 64, D_ / 64);

    hipLaunchKernelGGL(gemm_nt, gproj, blk, 0, stream, q, w_q, Q);
    hipLaunchKernelGGL(gemm_nt, gproj, blk, 0, stream, k, w_k, K);
    hipLaunchKernelGGL(gemm_nt, gproj, blk, 0, stream, v, w_v, V);

    dim3 gsc(S_ / 64, S_ / 64, B_ * H_);
    hipLaunchKernelGGL(scores_kernel, gsc, blk, 0, stream, Q, K, msk, P);

    hipLaunchKernelGGL(softmax_kernel, dim3(B_ * H_ * S_), blk, 0, stream, P);

    dim3 gpv(S_ / 64, B_ * H_);
    hipLaunchKernelGGL(pv_kernel, gpv, blk, 0, stream, P, V, A);

    hipLaunchKernelGGL(gemm_nt, gproj, blk, 0, stream, A, w_o, out);
}

// Round 5
// 1073.839 us; speedup vs baseline: 1.1116x; 1.1116x over previous
//
#include <hip/hip_runtime.h>
#include <hip/hip_bf16.h>
#include <cstdint>

// Problem constants (from reference)
constexpr int B_ = 4;
constexpr int S_ = 2048;
constexpr int D_ = 512;
constexpr int H_ = 8;
constexpr int DK_ = 64;
constexpr int M_ = B_ * S_;  // 8192 rows for projections

typedef __attribute__((ext_vector_type(8))) short bf16x8;
typedef __attribute__((ext_vector_type(4))) short bf16x4;
typedef __attribute__((ext_vector_type(4))) float f32x4;

__device__ __forceinline__ unsigned short f2bf(float x) {
    unsigned u = __float_as_uint(x);
    return (unsigned short)((u + 0x7fffu + ((u >> 16) & 1u)) >> 16);
}
__device__ __forceinline__ float bf2f(unsigned short h) {
    return __uint_as_float(((unsigned)h) << 16);
}

#define MFMA32(a, b, c) __builtin_amdgcn_mfma_f32_16x16x32_bf16(a, b, c, 0, 0, 0)

// ---------------------------------------------------------------------------
// GEMM_NT: C[i][j] = sum_d A[i][d] * W[j][d]   (fp32, unchanged from round 1)
// ---------------------------------------------------------------------------
__global__ __launch_bounds__(256) void gemm_nt(const float* __restrict__ A,
                                               const float* __restrict__ W,
                                               float* __restrict__ C) {
    constexpr int K = 512;
    __shared__ float As[32][65];
    __shared__ float Ws[32][65];
    const int tid = threadIdx.x;
    const int tx = tid & 15;
    const int ty = tid >> 4;
    const int bm = blockIdx.x * 64;
    const int bn = blockIdx.y * 64;

    float acc[4][4] = {};

    for (int k0 = 0; k0 < K; k0 += 32) {
#pragma unroll
        for (int l = 0; l < 2; ++l) {
            int idx = tid + l * 256;
            int r = idx >> 3;
            int c = (idx & 7) << 2;
            float4 av = *reinterpret_cast<const float4*>(&A[(size_t)(bm + r) * K + k0 + c]);
            As[c + 0][r] = av.x; As[c + 1][r] = av.y;
            As[c + 2][r] = av.z; As[c + 3][r] = av.w;
            float4 wv = *reinterpret_cast<const float4*>(&W[(size_t)(bn + r) * K + k0 + c]);
            Ws[c + 0][r] = wv.x; Ws[c + 1][r] = wv.y;
            Ws[c + 2][r] = wv.z; Ws[c + 3][r] = wv.w;
        }
        __syncthreads();
#pragma unroll
        for (int kk = 0; kk < 32; ++kk) {
            float a[4], w[4];
#pragma unroll
            for (int i = 0; i < 4; ++i) a[i] = As[kk][ty * 4 + i];
#pragma unroll
            for (int j = 0; j < 4; ++j) w[j] = Ws[kk][tx * 4 + j];
#pragma unroll
            for (int i = 0; i < 4; ++i)
#pragma unroll
                for (int j = 0; j < 4; ++j) acc[i][j] += a[i] * w[j];
        }
        __syncthreads();
    }

#pragma unroll
    for (int i = 0; i < 4; ++i) {
        int row = bm + ty * 4 + i;
        float4 o = make_float4(acc[i][0], acc[i][1], acc[i][2], acc[i][3]);
        *reinterpret_cast<float4*>(&C[(size_t)row * 512 + bn + tx * 4]) = o;
    }
}

// ---------------------------------------------------------------------------
// Stage a 64x64 fp32 tile (row stride 512) into hi/lo bf16 LDS tiles with
// XOR chunk swizzle: chunk (8 bf16 = 16B) c of row r stored at c ^ (r&7).
// ---------------------------------------------------------------------------
__device__ __forceinline__ void stage_hilo(const float* __restrict__ src,
                                           short* Hh, short* Hl, int tid) {
#pragma unroll
    for (int p = 0; p < 4; ++p) {
        int idx = tid + p * 256;
        int r = idx >> 4;
        int c4 = (idx & 15) * 4;
        float4 v = *reinterpret_cast<const float4*>(src + (size_t)r * 512 + c4);
        int off = r * 64 + ((((c4 >> 3)) ^ (r & 7)) << 3) + (c4 & 7);
        unsigned short h0 = f2bf(v.x), h1 = f2bf(v.y), h2 = f2bf(v.z), h3 = f2bf(v.w);
        bf16x4 hv = {(short)h0, (short)h1, (short)h2, (short)h3};
        bf16x4 lv = {(short)f2bf(v.x - bf2f(h0)), (short)f2bf(v.y - bf2f(h1)),
                     (short)f2bf(v.z - bf2f(h2)), (short)f2bf(v.w - bf2f(h3))};
        *(bf16x4*)(Hh + off) = hv;
        *(bf16x4*)(Hl + off) = lv;
    }
}

// ---------------------------------------------------------------------------
// Fused attention: scores (split-bf16 MFMA) + softmax (two-sweep online) + PV.
// Grid: (S/64 i-tiles, B*H). 256 threads = 4 waves, wave owns 16 q-rows.
// Writes normalized weights to P (the [B,H,S,S] output) exactly once, and
// the attention context (pre-W_o) to Ag.
// ---------------------------------------------------------------------------
__global__ __launch_bounds__(256, 2) void fused_attn(
    const float* __restrict__ Qg, const float* __restrict__ Kg,
    const float* __restrict__ Vg, const int* __restrict__ mask,
    float* __restrict__ P, float* __restrict__ Ag) {
    // LDS layout (bytes):
    //  region1: [0,9216)   VtT  : V^T bf16, 64 d-rows x 72 (pad) j-cols
    //           [9216,26624) Wl : 4 waves x [16][68] fp32 weight tiles
    //     (aliased during prologue: Qh [0,8192), Ql [8192,16384))
    //  region2: [26624,34816) Kh, [34816,43008) Kl
    __shared__ __align__(16) char smem[43008];
    short* VtT = (short*)smem;
    float* Wl  = (float*)(smem + 9216);
    short* Qh  = (short*)smem;
    short* Ql  = (short*)(smem + 8192);
    short* Kh  = (short*)(smem + 26624);
    short* Kl  = (short*)(smem + 34816);

    const int tid = threadIdx.x;
    const int wave = tid >> 6;
    const int lane = tid & 63;
    const int lg = lane >> 4;   // 0..3
    const int lr = lane & 15;   // 0..15
    const int bh = blockIdx.y;
    const int b = bh >> 3;
    const int h = bh & 7;
    const int i0 = blockIdx.x * 64;
    const unsigned char* mb = (const unsigned char*)mask;  // LSB of little-endian int

    // ---- stage Q tile, load A-frags into registers
    stage_hilo(Qg + ((size_t)(b * S_ + i0)) * D_ + h * DK_, Qh, Ql, tid);
    __syncthreads();

    bf16x8 qh[2], ql[2];
    {
        int r = wave * 16 + lr;
#pragma unroll
        for (int ks = 0; ks < 2; ++ks) {
            int off = r * 64 + (((ks * 4 + lg) ^ (r & 7)) << 3);
            qh[ks] = *(const bf16x8*)(Qh + off);
            ql[ks] = *(const bf16x8*)(Ql + off);
        }
    }
    __syncthreads();  // everyone done reading Q region before VtT/Wl reuse

    const int gi_base = i0 + wave * 16 + lg * 4;  // + rr

    // =========================== sweep 1: row stats ===========================
    float m_[4] = {-1e30f, -1e30f, -1e30f, -1e30f};
    float l_[4] = {0.f, 0.f, 0.f, 0.f};

    for (int t = 0; t < 32; ++t) {
        const int j0 = t * 64;
        stage_hilo(Kg + ((size_t)(b * S_ + j0)) * D_ + h * DK_, Kh, Kl, tid);
        __syncthreads();

        float sv[4][4];
#pragma unroll
        for (int jt = 0; jt < 4; ++jt) {
            f32x4 s = (f32x4){0.f, 0.f, 0.f, 0.f};
            int r = jt * 16 + lr;
#pragma unroll
            for (int ks = 0; ks < 2; ++ks) {
                int off = r * 64 + (((ks * 4 + lg) ^ (r & 7)) << 3);
                bf16x8 kh = *(const bf16x8*)(Kh + off);
                bf16x8 kl = *(const bf16x8*)(Kl + off);
                s = MFMA32(qh[ks], kh, s);
                s = MFMA32(qh[ks], kl, s);
                s = MFMA32(ql[ks], kh, s);
            }
#pragma unroll
            for (int rr = 0; rr < 4; ++rr) {
                int gi = gi_base + rr;
                size_t midx = (((size_t)(b * S_ + gi)) * S_ + (j0 + jt * 16 + lr)) << 2;
                bool mk = mb[midx] != 0;
                sv[jt][rr] = mk ? -1e30f : s[rr] * 0.125f;
            }
        }
#pragma unroll
        for (int rr = 0; rr < 4; ++rr) {
            float tm = fmaxf(fmaxf(sv[0][rr], sv[1][rr]), fmaxf(sv[2][rr], sv[3][rr]));
            tm = fmaxf(tm, __shfl_xor(tm, 1));
            tm = fmaxf(tm, __shfl_xor(tm, 2));
            tm = fmaxf(tm, __shfl_xor(tm, 4));
            tm = fmaxf(tm, __shfl_xor(tm, 8));
            float nm = fmaxf(m_[rr], tm);
            float fac = __expf(m_[rr] - nm);
            float ts = 0.f;
#pragma unroll
            for (int jt = 0; jt < 4; ++jt)
                ts += (sv[jt][rr] > -1e29f) ? __expf(sv[jt][rr] - nm) : 0.f;
            ts += __shfl_xor(ts, 1);
            ts += __shfl_xor(ts, 2);
            ts += __shfl_xor(ts, 4);
            ts += __shfl_xor(ts, 8);
            l_[rr] = l_[rr] * fac + ts;
            m_[rr] = nm;
        }
        __syncthreads();
    }

    float invl[4];
#pragma unroll
    for (int rr = 0; rr < 4; ++rr) invl[rr] = 1.0f / fmaxf(l_[rr], 1e-37f);

    // =========================== sweep 2: weights + PV ===========================
    float* wrow = Wl + wave * (16 * 68);
    f32x4 Oa[4];
#pragma unroll
    for (int dt = 0; dt < 4; ++dt) Oa[dt] = (f32x4){0.f, 0.f, 0.f, 0.f};

    for (int t = 0; t < 32; ++t) {
        const int j0 = t * 64;
        stage_hilo(Kg + ((size_t)(b * S_ + j0)) * D_ + h * DK_, Kh, Kl, tid);
        // stage V transposed: VtT[d][j] bf16, row stride 72 (16B-aligned b128 reads)
        {
            const float* src = Vg + ((size_t)(b * S_ + j0)) * D_ + h * DK_;
#pragma unroll
            for (int p = 0; p < 4; ++p) {
                int idx = tid + p * 256;
                int d = idx & 63;            // lane-consecutive -> coalesced loads
                int j4 = (idx >> 6) * 4;     // 0,4,...,60
                float v0 = src[(size_t)(j4 + 0) * D_ + d];
                float v1 = src[(size_t)(j4 + 1) * D_ + d];
                float v2 = src[(size_t)(j4 + 2) * D_ + d];
                float v3 = src[(size_t)(j4 + 3) * D_ + d];
                bf16x4 bv = {(short)f2bf(v0), (short)f2bf(v1),
                             (short)f2bf(v2), (short)f2bf(v3)};
                *(bf16x4*)(VtT + d * 72 + j4) = bv;
            }
        }
        __syncthreads();

        // QK^T (recompute) -> normalized weights into per-wave LDS tile
#pragma unroll
        for (int jt = 0; jt < 4; ++jt) {
            f32x4 s = (f32x4){0.f, 0.f, 0.f, 0.f};
            int r = jt * 16 + lr;
#pragma unroll
            for (int ks = 0; ks < 2; ++ks) {
                int off = r * 64 + (((ks * 4 + lg) ^ (r & 7)) << 3);
                bf16x8 kh = *(const bf16x8*)(Kh + off);
                bf16x8 kl = *(const bf16x8*)(Kl + off);
                s = MFMA32(qh[ks], kh, s);
                s = MFMA32(qh[ks], kl, s);
                s = MFMA32(ql[ks], kh, s);
            }
#pragma unroll
            for (int rr = 0; rr < 4; ++rr) {
                int gi = gi_base + rr;
                size_t midx = (((size_t)(b * S_ + gi)) * S_ + (j0 + jt * 16 + lr)) << 2;
                bool mk = mb[midx] != 0;
                float w = mk ? 0.f : __expf(s[rr] * 0.125f - m_[rr]) * invl[rr];
                wrow[(lg * 4 + rr) * 68 + jt * 16 + lr] = w;
            }
        }

        // coalesced P write from the per-wave LDS tile
        {
            float* Prow = P + ((size_t)bh * S_ + (i0 + wave * 16)) * S_ + j0;
#pragma unroll
            for (int p2 = 0; p2 < 4; ++p2) {
                int row = p2 * 4 + lg;
                f32x4 pv = *(const f32x4*)(wrow + row * 68 + lr * 4);
                *(f32x4*)(Prow + (size_t)row * S_ + lr * 4) = pv;
            }
        }

        // PV: A = W (LDS->bf16, 8-wide), B = V^T rows from VtT (plain b128 reads)
        bf16x8 aw[2];
#pragma unroll
        for (int ks2 = 0; ks2 < 2; ++ks2) {
            f32x4 w0 = *(const f32x4*)(wrow + lr * 68 + ks2 * 32 + lg * 8);
            f32x4 w1 = *(const f32x4*)(wrow + lr * 68 + ks2 * 32 + lg * 8 + 4);
            aw[ks2] = (bf16x8){(short)f2bf(w0.x), (short)f2bf(w0.y),
                               (short)f2bf(w0.z), (short)f2bf(w0.w),
                               (short)f2bf(w1.x), (short)f2bf(w1.y),
                               (short)f2bf(w1.z), (short)f2bf(w1.w)};
        }
#pragma unroll
        for (int dt = 0; dt < 4; ++dt) {
#pragma unroll
            for (int ks2 = 0; ks2 < 2; ++ks2) {
                bf16x8 vv = *(const bf16x8*)(VtT + (dt * 16 + lr) * 72 + ks2 * 32 + lg * 8);
                Oa[dt] = MFMA32(aw[ks2], vv, Oa[dt]);
            }
        }

        __syncthreads();
    }

    // write attention context (pre-W_o)
    {
        float* Ab = Ag + ((size_t)(b * S_)) * D_ + h * DK_;
#pragma unroll
        for (int dt = 0; dt < 4; ++dt)
#pragma unroll
            for (int rr = 0; rr < 4; ++rr) {
                int gi = i0 + wave * 16 + lg * 4 + rr;
                Ab[(size_t)gi * D_ + dt * 16 + lr] = Oa[dt][rr];
            }
    }
}

// ---------------------------------------------------------------------------
extern "C" void kernel_launch(void* const* d_in, const int* in_sizes, int n_in,
                              void* d_out, int out_size, void* d_ws, size_t ws_size,
                              hipStream_t stream) {
    const float* q   = (const float*)d_in[0];
    const float* k   = (const float*)d_in[1];
    const float* v   = (const float*)d_in[2];
    const int*   msk = (const int*)d_in[3];
    const float* w_q = (const float*)d_in[4];
    const float* w_k = (const float*)d_in[5];
    const float* w_v = (const float*)d_in[6];
    const float* w_o = (const float*)d_in[7];

    float* out = (float*)d_out;                       // [B,S,D]
    float* P   = out + (size_t)B_ * S_ * D_;          // [B,H,S,S] attention weights

    float* ws = (float*)d_ws;
    float* Q  = ws;                                   // [B,S,D]
    float* K  = Q + (size_t)M_ * D_;                  // [B,S,D]
    float* V  = K + (size_t)M_ * D_;                  // [B,S,D]
    float* A  = V + (size_t)M_ * D_;                  // [B,S,D] attn (pre w_o)

    dim3 blk(256);
    dim3 gproj(M_ / 64, D_ / 64);

    hipLaunchKernelGGL(gemm_nt, gproj, blk, 0, stream, q, w_q, Q);
    hipLaunchKernelGGL(gemm_nt, gproj, blk, 0, stream, k, w_k, K);
    hipLaunchKernelGGL(gemm_nt, gproj, blk, 0, stream, v, w_v, V);

    dim3 gattn(S_ / 64, B_ * H_);
    hipLaunchKernelGGL(fused_attn, gattn, blk, 0, stream, Q, K, V, msk, P, A);

    hipLaunchKernelGGL(gemm_nt, gproj, blk, 0, stream, A, w_o, out);
}

// Round 6
// 752.842 us; speedup vs baseline: 1.5855x; 1.4264x over previous
//
#include <hip/hip_runtime.h>
#include <hip/hip_bf16.h>
#include <cstdint>

constexpr int B_ = 4;
constexpr int S_ = 2048;
constexpr int D_ = 512;
constexpr int H_ = 8;
constexpr int DK_ = 64;
constexpr int M_ = B_ * S_;

typedef __attribute__((ext_vector_type(8))) short bf16x8;
typedef __attribute__((ext_vector_type(4))) short bf16x4;
typedef __attribute__((ext_vector_type(4))) float f32x4;

__device__ __forceinline__ unsigned short f2bf(float x) {
    unsigned u = __float_as_uint(x);
    return (unsigned short)((u + 0x7fffu + ((u >> 16) & 1u)) >> 16);
}
__device__ __forceinline__ float bf2f(unsigned short h) {
    return __uint_as_float(((unsigned)h) << 16);
}

#define MFMA32(a, b, c) __builtin_amdgcn_mfma_f32_16x16x32_bf16(a, b, c, 0, 0, 0)

// ---------------------------------------------------------------------------
// GEMM_NT (fp32, unchanged): C[i][j] = sum_d A[i][d] * W[j][d]
// ---------------------------------------------------------------------------
__global__ __launch_bounds__(256) void gemm_nt(const float* __restrict__ A,
                                               const float* __restrict__ W,
                                               float* __restrict__ C) {
    constexpr int K = 512;
    __shared__ float As[32][65];
    __shared__ float Ws[32][65];
    const int tid = threadIdx.x;
    const int tx = tid & 15;
    const int ty = tid >> 4;
    const int bm = blockIdx.x * 64;
    const int bn = blockIdx.y * 64;

    float acc[4][4] = {};

    for (int k0 = 0; k0 < K; k0 += 32) {
#pragma unroll
        for (int l = 0; l < 2; ++l) {
            int idx = tid + l * 256;
            int r = idx >> 3;
            int c = (idx & 7) << 2;
            float4 av = *reinterpret_cast<const float4*>(&A[(size_t)(bm + r) * K + k0 + c]);
            As[c + 0][r] = av.x; As[c + 1][r] = av.y;
            As[c + 2][r] = av.z; As[c + 3][r] = av.w;
            float4 wv = *reinterpret_cast<const float4*>(&W[(size_t)(bn + r) * K + k0 + c]);
            Ws[c + 0][r] = wv.x; Ws[c + 1][r] = wv.y;
            Ws[c + 2][r] = wv.z; Ws[c + 3][r] = wv.w;
        }
        __syncthreads();
#pragma unroll
        for (int kk = 0; kk < 32; ++kk) {
            float a[4], w[4];
#pragma unroll
            for (int i = 0; i < 4; ++i) a[i] = As[kk][ty * 4 + i];
#pragma unroll
            for (int j = 0; j < 4; ++j) w[j] = Ws[kk][tx * 4 + j];
#pragma unroll
            for (int i = 0; i < 4; ++i)
#pragma unroll
                for (int j = 0; j < 4; ++j) acc[i][j] += a[i] * w[j];
        }
        __syncthreads();
    }

#pragma unroll
    for (int i = 0; i < 4; ++i) {
        int row = bm + ty * 4 + i;
        float4 o = make_float4(acc[i][0], acc[i][1], acc[i][2], acc[i][3]);
        *reinterpret_cast<float4*>(&C[(size_t)row * 512 + bn + tx * 4]) = o;
    }
}

// ---------------------------------------------------------------------------
// cvt_hilo: X fp32 [8192][512] -> Xh, Xl bf16 head-major [(b*8+h)*2048 + s][64]
// ---------------------------------------------------------------------------
__global__ __launch_bounds__(256) void cvt_hilo(const float* __restrict__ X,
                                                short* __restrict__ Xh,
                                                short* __restrict__ Xl) {
    int idx = blockIdx.x * 256 + threadIdx.x;   // 8192*64 total
    int r = idx >> 6;          // row (b*2048+s)
    int g = idx & 63;          // 8-float group
    int b = r >> 11, s = r & 2047;
    int h = g >> 3, dk0 = (g & 7) * 8;
    const float* src = X + (size_t)r * 512 + g * 8;
    float4 v0 = *reinterpret_cast<const float4*>(src);
    float4 v1 = *reinterpret_cast<const float4*>(src + 4);
    float f[8] = {v0.x, v0.y, v0.z, v0.w, v1.x, v1.y, v1.z, v1.w};
    short hh[8], ll[8];
#pragma unroll
    for (int e = 0; e < 8; ++e) {
        unsigned short hb = f2bf(f[e]);
        hh[e] = (short)hb;
        ll[e] = (short)f2bf(f[e] - bf2f(hb));
    }
    size_t out = ((size_t)((b * 8 + h) * 2048 + s)) * 64 + dk0;
    *(bf16x4*)(Xh + out)     = (bf16x4){hh[0], hh[1], hh[2], hh[3]};
    *(bf16x4*)(Xh + out + 4) = (bf16x4){hh[4], hh[5], hh[6], hh[7]};
    *(bf16x4*)(Xl + out)     = (bf16x4){ll[0], ll[1], ll[2], ll[3]};
    *(bf16x4*)(Xl + out + 4) = (bf16x4){ll[4], ll[5], ll[6], ll[7]};
}

// ---------------------------------------------------------------------------
// vt_kernel: V fp32 [B,S,D] -> Vt bf16 [(b*8+h)*64 + dk][2048]  (V transposed)
// ---------------------------------------------------------------------------
__global__ __launch_bounds__(256) void vt_kernel(const float* __restrict__ V,
                                                 short* __restrict__ Vt) {
    __shared__ short tile[64][72];
    const int bh = blockIdx.y;
    const int b = bh >> 3, h = bh & 7;
    const int j0 = blockIdx.x * 64;
    const int tid = threadIdx.x;
    {
        int jj = tid >> 2;
        int c = (tid & 3) * 16;
        const float* src = V + ((size_t)(b * 2048 + j0 + jj)) * 512 + h * 64 + c;
#pragma unroll
        for (int q = 0; q < 4; ++q) {
            float4 v = *reinterpret_cast<const float4*>(src + q * 4);
            tile[jj][c + q * 4 + 0] = (short)f2bf(v.x);
            tile[jj][c + q * 4 + 1] = (short)f2bf(v.y);
            tile[jj][c + q * 4 + 2] = (short)f2bf(v.z);
            tile[jj][c + q * 4 + 3] = (short)f2bf(v.w);
        }
    }
    __syncthreads();
    {
        int dk = tid >> 2;
        int jq = (tid & 3) * 16;
        short* dst = Vt + ((size_t)(bh * 64 + dk)) * 2048 + j0 + jq;
#pragma unroll
        for (int q = 0; q < 4; ++q) {
            bf16x4 o = {tile[jq + q * 4 + 0][dk], tile[jq + q * 4 + 1][dk],
                        tile[jq + q * 4 + 2][dk], tile[jq + q * 4 + 3][dk]};
            *(bf16x4*)(dst + q * 4) = o;
        }
    }
}

// ---------------------------------------------------------------------------
// mask_pack: mask int32 [B,1,S,S] -> pk u64 [b*2048+i][32], bit jl = mask!=0
// ---------------------------------------------------------------------------
__global__ __launch_bounds__(256) void mask_pack(const int* __restrict__ mask,
                                                 unsigned long long* __restrict__ pk) {
    const int row = blockIdx.x;               // b*2048 + i
    const int tid = threadIdx.x;
    const int* mrow = mask + (size_t)row * 2048;
#pragma unroll
    for (int p = 0; p < 8; ++p) {
        int j = p * 256 + tid;
        unsigned long long bal = __ballot(mrow[j] != 0);
        if ((tid & 63) == 0) pk[(size_t)row * 32 + p * 4 + (tid >> 6)] = bal;
    }
}

// ---------------------------------------------------------------------------
// Fused attention v2: pre-converted bf16 inputs, packed mask, 1 barrier/iter.
// Grid (32 i-tiles, 32 bh), 256 threads = 4 waves, wave owns 16 q-rows.
// ---------------------------------------------------------------------------
__global__ __launch_bounds__(256, 3) void fused_attn(
    const short* __restrict__ Qh_g, const short* __restrict__ Ql_g,
    const short* __restrict__ Kh_g, const short* __restrict__ Kl_g,
    const short* __restrict__ Vt_g, const unsigned long long* __restrict__ pk,
    float* __restrict__ P, float* __restrict__ Ag) {
    __shared__ __align__(16) short Kbuf[2][2][4096];  // [dbuf][hi/lo][64*64], XOR-swz
    __shared__ __align__(16) short Wt[4096];          // weights bf16 [64][64], XOR-swz

    const int tid = threadIdx.x;
    const int wave = tid >> 6;
    const int lane = tid & 63;
    const int lg = lane >> 4;
    const int lr = lane & 15;
    const int bh = blockIdx.y;
    const int b = bh >> 3;
    const int i0 = blockIdx.x * 64;

    // Q fragments direct from global (head-major, plain layout)
    bf16x8 qh[2], ql[2];
    {
        const size_t qbase = ((size_t)bh * 2048 + i0 + wave * 16 + lr) * 64;
#pragma unroll
        for (int ks = 0; ks < 2; ++ks) {
            qh[ks] = *(const bf16x8*)(Qh_g + qbase + (ks * 4 + lg) * 8);
            ql[ks] = *(const bf16x8*)(Ql_g + qbase + (ks * 4 + lg) * 8);
        }
    }

    // staging offsets: thread copies 2x16B per 8KB tile (linear global, swz LDS)
    const int o0 = tid * 16;
    const int o1 = 4096 + tid * 16;
    const int s0 = o0 ^ (((o0 >> 7) & 7) << 4);
    const int s1 = o1 ^ (((o1 >> 7) & 7) << 4);

    bf16x8 Rh0, Rh1, Rl0, Rl1;
#define LOADK(t)                                                            \
    {                                                                       \
        const short* bKh = Kh_g + ((size_t)bh * 2048 + (t) * 64) * 64;      \
        const short* bKl = Kl_g + ((size_t)bh * 2048 + (t) * 64) * 64;      \
        Rh0 = *(const bf16x8*)(bKh + (o0 >> 1));                            \
        Rh1 = *(const bf16x8*)(bKh + (o1 >> 1));                            \
        Rl0 = *(const bf16x8*)(bKl + (o0 >> 1));                            \
        Rl1 = *(const bf16x8*)(bKl + (o1 >> 1));                            \
    }
#define WRITEK(cur)                                                         \
    {                                                                       \
        *(bf16x8*)(&Kbuf[cur][0][0] + (s0 >> 1)) = Rh0;                     \
        *(bf16x8*)(&Kbuf[cur][0][0] + (s1 >> 1)) = Rh1;                     \
        *(bf16x8*)(&Kbuf[cur][1][0] + (s0 >> 1)) = Rl0;                     \
        *(bf16x8*)(&Kbuf[cur][1][0] + (s1 >> 1)) = Rl1;                     \
    }

    const int gi_row = i0 + wave * 16 + lg * 4;     // + rr
    const size_t pkrow = (size_t)b * 2048 + gi_row; // + rr

    // ========================= sweep 1: row stats =========================
    float m_[4] = {-1e30f, -1e30f, -1e30f, -1e30f};
    float l_[4] = {0.f, 0.f, 0.f, 0.f};

    LOADK(0);
    for (int t = 0; t < 32; ++t) {
        const int cur = t & 1;
        WRITEK(cur);
        if (t < 31) LOADK(t + 1);
        unsigned long long pkv[4];
#pragma unroll
        for (int rr = 0; rr < 4; ++rr) pkv[rr] = pk[(pkrow + rr) * 32 + t];
        __syncthreads();

        const short* KH = &Kbuf[cur][0][0];
        const short* KL = &Kbuf[cur][1][0];
        float sv[4][4];
#pragma unroll
        for (int jt = 0; jt < 4; ++jt) {
            f32x4 s = (f32x4){0.f, 0.f, 0.f, 0.f};
            int r = jt * 16 + lr;
#pragma unroll
            for (int ks = 0; ks < 2; ++ks) {
                int off = (r * 128 + (ks * 4 + lg) * 16) ^ ((r & 7) << 4);
                bf16x8 kh = *(const bf16x8*)(KH + (off >> 1));
                bf16x8 kl = *(const bf16x8*)(KL + (off >> 1));
                s = MFMA32(qh[ks], kh, s);
                s = MFMA32(qh[ks], kl, s);
                s = MFMA32(ql[ks], kh, s);
            }
#pragma unroll
            for (int rr = 0; rr < 4; ++rr) {
                bool mk = (pkv[rr] >> (jt * 16 + lr)) & 1ull;
                sv[jt][rr] = mk ? -1e30f : s[rr] * 0.125f;
            }
        }
#pragma unroll
        for (int rr = 0; rr < 4; ++rr) {
            float tm = fmaxf(fmaxf(sv[0][rr], sv[1][rr]), fmaxf(sv[2][rr], sv[3][rr]));
            tm = fmaxf(tm, __shfl_xor(tm, 1));
            tm = fmaxf(tm, __shfl_xor(tm, 2));
            tm = fmaxf(tm, __shfl_xor(tm, 4));
            tm = fmaxf(tm, __shfl_xor(tm, 8));
            float nm = fmaxf(m_[rr], tm);
            float fac = __expf(m_[rr] - nm);
            float ts = 0.f;
#pragma unroll
            for (int jt = 0; jt < 4; ++jt)
                ts += (sv[jt][rr] > -1e29f) ? __expf(sv[jt][rr] - nm) : 0.f;
            ts += __shfl_xor(ts, 1);
            ts += __shfl_xor(ts, 2);
            ts += __shfl_xor(ts, 4);
            ts += __shfl_xor(ts, 8);
            l_[rr] = l_[rr] * fac + ts;
            m_[rr] = nm;
        }
    }

    float invl[4];
#pragma unroll
    for (int rr = 0; rr < 4; ++rr) invl[rr] = 1.0f / fmaxf(l_[rr], 1e-37f);

    // ====================== sweep 2: weights + P + PV ======================
    f32x4 Oa[4];
#pragma unroll
    for (int dt = 0; dt < 4; ++dt) Oa[dt] = (f32x4){0.f, 0.f, 0.f, 0.f};

    LOADK(0);
    for (int t = 0; t < 32; ++t) {
        const int cur = t & 1;
        WRITEK(cur);
        if (t < 31) LOADK(t + 1);
        unsigned long long pkv[4];
#pragma unroll
        for (int rr = 0; rr < 4; ++rr) pkv[rr] = pk[(pkrow + rr) * 32 + t];
        // V fragments for this tile, direct from global (consumed at iter end)
        bf16x8 vf[4][2];
#pragma unroll
        for (int dt = 0; dt < 4; ++dt)
#pragma unroll
            for (int ks2 = 0; ks2 < 2; ++ks2)
                vf[dt][ks2] = *(const bf16x8*)(Vt_g +
                    ((size_t)(bh * 64 + dt * 16 + lr)) * 2048 + t * 64 + (ks2 * 4 + lg) * 8);
        __syncthreads();

        const short* KH = &Kbuf[cur][0][0];
        const short* KL = &Kbuf[cur][1][0];
        // scores -> normalized weights (bf16) into Wt (wave-private rows)
#pragma unroll
        for (int jt = 0; jt < 4; ++jt) {
            f32x4 s = (f32x4){0.f, 0.f, 0.f, 0.f};
            int r = jt * 16 + lr;
#pragma unroll
            for (int ks = 0; ks < 2; ++ks) {
                int off = (r * 128 + (ks * 4 + lg) * 16) ^ ((r & 7) << 4);
                bf16x8 kh = *(const bf16x8*)(KH + (off >> 1));
                bf16x8 kl = *(const bf16x8*)(KL + (off >> 1));
                s = MFMA32(qh[ks], kh, s);
                s = MFMA32(qh[ks], kl, s);
                s = MFMA32(ql[ks], kh, s);
            }
#pragma unroll
            for (int rr = 0; rr < 4; ++rr) {
                bool mk = (pkv[rr] >> (jt * 16 + lr)) & 1ull;
                float w = mk ? 0.f : __expf(s[rr] * 0.125f - m_[rr]) * invl[rr];
                int rw = wave * 16 + lg * 4 + rr;
                int wo = rw * 64 + (((jt * 2 + (lr >> 3)) ^ (rw & 7)) << 3) + (lr & 7);
                Wt[wo] = (short)f2bf(w);
            }
        }

        // P write (wave-own rows): bf16 Wt -> fp32, fully coalesced 16B stores
        {
            int rp = wave * 16 + (lane >> 2);
            int c2 = (lane & 3) * 2;
            int po0 = rp * 64 + (((c2 + 0) ^ (rp & 7)) << 3);
            int po1 = rp * 64 + (((c2 + 1) ^ (rp & 7)) << 3);
            bf16x8 wa = *(const bf16x8*)(Wt + po0);
            bf16x8 wb = *(const bf16x8*)(Wt + po1);
            float* Prow = P + ((size_t)bh * 2048 + i0 + rp) * 2048 + t * 64 + (lane & 3) * 16;
#pragma unroll
            for (int q = 0; q < 2; ++q) {
                f32x4 oA = {bf2f((unsigned short)wa[q * 4 + 0]), bf2f((unsigned short)wa[q * 4 + 1]),
                            bf2f((unsigned short)wa[q * 4 + 2]), bf2f((unsigned short)wa[q * 4 + 3])};
                f32x4 oB = {bf2f((unsigned short)wb[q * 4 + 0]), bf2f((unsigned short)wb[q * 4 + 1]),
                            bf2f((unsigned short)wb[q * 4 + 2]), bf2f((unsigned short)wb[q * 4 + 3])};
                *(f32x4*)(Prow + q * 4) = oA;
                *(f32x4*)(Prow + 8 + q * 4) = oB;
            }
        }

        // PV: A-frag = wave's own Wt rows, B-frag = V^T from registers
        bf16x8 aw[2];
#pragma unroll
        for (int ks2 = 0; ks2 < 2; ++ks2) {
            int ra = wave * 16 + lr;
            int ao = ra * 64 + (((ks2 * 4 + lg) ^ (ra & 7)) << 3);
            aw[ks2] = *(const bf16x8*)(Wt + ao);
        }
#pragma unroll
        for (int dt = 0; dt < 4; ++dt)
#pragma unroll
            for (int ks2 = 0; ks2 < 2; ++ks2)
                Oa[dt] = MFMA32(aw[ks2], vf[dt][ks2], Oa[dt]);
    }

    // context (pre-W_o) out
    {
        const int h = bh & 7;
        float* Ab = Ag + ((size_t)(b * S_)) * D_ + h * DK_;
#pragma unroll
        for (int dt = 0; dt < 4; ++dt)
#pragma unroll
            for (int rr = 0; rr < 4; ++rr) {
                int gi = i0 + wave * 16 + lg * 4 + rr;
                Ab[(size_t)gi * D_ + dt * 16 + lr] = Oa[dt][rr];
            }
    }
#undef LOADK
#undef WRITEK
}

// ---------------------------------------------------------------------------
extern "C" void kernel_launch(void* const* d_in, const int* in_sizes, int n_in,
                              void* d_out, int out_size, void* d_ws, size_t ws_size,
                              hipStream_t stream) {
    const float* q   = (const float*)d_in[0];
    const float* k   = (const float*)d_in[1];
    const float* v   = (const float*)d_in[2];
    const int*   msk = (const int*)d_in[3];
    const float* w_q = (const float*)d_in[4];
    const float* w_k = (const float*)d_in[5];
    const float* w_v = (const float*)d_in[6];
    const float* w_o = (const float*)d_in[7];

    float* out = (float*)d_out;                 // [B,S,D]
    float* P   = out + (size_t)B_ * S_ * D_;    // [B,H,S,S]

    float* ws = (float*)d_ws;
    float* Qf = ws;                             // [8192][512] fp32
    float* Kf = Qf + (size_t)M_ * D_;
    float* Vf = Kf + (size_t)M_ * D_;
    short* S0 = (short*)(Vf + (size_t)M_ * D_);
    short* Qh = S0;                             // [32][2048][64] bf16 head-major
    short* Ql = Qh + (size_t)M_ * DK_ * H_ / H_ * 1;  // == +4194304
    Ql = Qh + (size_t)4194304;
    short* Kh = Ql + (size_t)4194304;
    short* Kl = Kh + (size_t)4194304;
    short* Vt = Kl + (size_t)4194304;           // [32][64][2048] bf16 (V^T)
    unsigned long long* pk = (unsigned long long*)(Vt + (size_t)4194304);
    float* A = Qf;                              // context aliases Qf (safe: Qf only read by cvt)

    dim3 blk(256);
    dim3 gproj(M_ / 64, D_ / 64);

    hipLaunchKernelGGL(gemm_nt, gproj, blk, 0, stream, q, w_q, Qf);
    hipLaunchKernelGGL(gemm_nt, gproj, blk, 0, stream, k, w_k, Kf);
    hipLaunchKernelGGL(gemm_nt, gproj, blk, 0, stream, v, w_v, Vf);

    hipLaunchKernelGGL(cvt_hilo, dim3(2048), blk, 0, stream, Qf, Qh, Ql);
    hipLaunchKernelGGL(cvt_hilo, dim3(2048), blk, 0, stream, Kf, Kh, Kl);
    hipLaunchKernelGGL(vt_kernel, dim3(32, 32), blk, 0, stream, Vf, Vt);
    hipLaunchKernelGGL(mask_pack, dim3(M_), blk, 0, stream, msk, pk);

    hipLaunchKernelGGL(fused_attn, dim3(32, 32), blk, 0, stream,
                       Qh, Ql, Kh, Kl, Vt, pk, P, A);

    hipLaunchKernelGGL(gemm_nt, gproj, blk, 0, stream, A, w_o, out);
}

// Round 7
// 632.907 us; speedup vs baseline: 1.8859x; 1.1895x over previous
//
#include <hip/hip_runtime.h>
#include <hip/hip_bf16.h>
#include <cstdint>

constexpr int B_ = 4;
constexpr int S_ = 2048;
constexpr int D_ = 512;
constexpr int H_ = 8;
constexpr int DK_ = 64;
constexpr int M_ = B_ * S_;

typedef __attribute__((ext_vector_type(8))) short bf16x8;
typedef __attribute__((ext_vector_type(4))) short bf16x4;
typedef __attribute__((ext_vector_type(4))) float f32x4;

__device__ __forceinline__ unsigned short f2bf(float x) {
    unsigned u = __float_as_uint(x);
    return (unsigned short)((u + 0x7fffu + ((u >> 16) & 1u)) >> 16);
}
__device__ __forceinline__ float bf2f(unsigned short h) {
    return __uint_as_float(((unsigned)h) << 16);
}

#define MFMA32(a, b, c) __builtin_amdgcn_mfma_f32_16x16x32_bf16(a, b, c, 0, 0, 0)

// ---------------------------------------------------------------------------
// stage_hilo: 64x64 fp32 tile (row stride 512) -> hi/lo bf16 LDS tiles,
// XOR chunk swizzle: 16B chunk c of row r stored at chunk c ^ (r&7).
// (verified in rounds 5/6)
// ---------------------------------------------------------------------------
__device__ __forceinline__ void stage_hilo(const float* __restrict__ src,
                                           short* Hh, short* Hl, int tid) {
#pragma unroll
    for (int p = 0; p < 4; ++p) {
        int idx = tid + p * 256;
        int r = idx >> 4;
        int c4 = (idx & 15) * 4;
        float4 v = *reinterpret_cast<const float4*>(src + (size_t)r * 512 + c4);
        int off = r * 64 + ((((c4 >> 3)) ^ (r & 7)) << 3) + (c4 & 7);
        unsigned short h0 = f2bf(v.x), h1 = f2bf(v.y), h2 = f2bf(v.z), h3 = f2bf(v.w);
        bf16x4 hv = {(short)h0, (short)h1, (short)h2, (short)h3};
        bf16x4 lv = {(short)f2bf(v.x - bf2f(h0)), (short)f2bf(v.y - bf2f(h1)),
                     (short)f2bf(v.z - bf2f(h2)), (short)f2bf(v.w - bf2f(h3))};
        *(bf16x4*)(Hh + off) = hv;
        *(bf16x4*)(Hl + off) = lv;
    }
}

// ---------------------------------------------------------------------------
// gemm_nt_mfma: C[m][n] = sum_k A[m][k] * W[n][k]  (split-bf16 MFMA)
// A [M,512], W [512,512], C [M,512]. BM=128, BN=64, BK=64.
// grid (M/128, 512/64) = (64, 8), 256 threads = 4 waves.
// Wave w owns rows [bm + w*32, +32) x all 64 n-cols. acc[2][4] f32x4.
// ---------------------------------------------------------------------------
__global__ __launch_bounds__(256) void gemm_nt_mfma(const float* __restrict__ A,
                                                    const float* __restrict__ W,
                                                    float* __restrict__ C) {
    __shared__ __align__(16) short Ah[8192];  // [128][64] bf16, swizzled
    __shared__ __align__(16) short Al[8192];
    __shared__ __align__(16) short Wh[4096];  // [64][64]
    __shared__ __align__(16) short Wl[4096];

    const int tid = threadIdx.x;
    const int wave = tid >> 6;
    const int lane = tid & 63;
    const int lg = lane >> 4;   // 0..3
    const int lr = lane & 15;   // 0..15
    const int bm = blockIdx.x * 128;
    const int bn = blockIdx.y * 64;

    f32x4 acc[2][4];
#pragma unroll
    for (int s = 0; s < 2; ++s)
#pragma unroll
        for (int n = 0; n < 4; ++n) acc[s][n] = (f32x4){0.f, 0.f, 0.f, 0.f};

    for (int k0 = 0; k0 < 512; k0 += 64) {
        stage_hilo(A + (size_t)bm * 512 + k0, Ah, Al, tid);
        stage_hilo(A + (size_t)(bm + 64) * 512 + k0, Ah + 4096, Al + 4096, tid);
        stage_hilo(W + (size_t)bn * 512 + k0, Wh, Wl, tid);
        __syncthreads();

#pragma unroll
        for (int ks = 0; ks < 2; ++ks) {
            bf16x8 ah[2], al[2];
#pragma unroll
            for (int sub = 0; sub < 2; ++sub) {
                int r = wave * 32 + sub * 16 + lr;
                int off = r * 64 + (((ks * 4 + lg) ^ (r & 7)) << 3);
                ah[sub] = *(const bf16x8*)(Ah + off);
                al[sub] = *(const bf16x8*)(Al + off);
            }
#pragma unroll
            for (int nsub = 0; nsub < 4; ++nsub) {
                int r = nsub * 16 + lr;
                int off = r * 64 + (((ks * 4 + lg) ^ (r & 7)) << 3);
                bf16x8 wh = *(const bf16x8*)(Wh + off);
                bf16x8 wl = *(const bf16x8*)(Wl + off);
#pragma unroll
                for (int sub = 0; sub < 2; ++sub) {
                    acc[sub][nsub] = MFMA32(ah[sub], wh, acc[sub][nsub]);
                    acc[sub][nsub] = MFMA32(ah[sub], wl, acc[sub][nsub]);
                    acc[sub][nsub] = MFMA32(al[sub], wh, acc[sub][nsub]);
                }
            }
        }
        __syncthreads();
    }

    // C-write: row = bm + wave*32 + sub*16 + lg*4 + rr, col = bn + nsub*16 + lr
#pragma unroll
    for (int sub = 0; sub < 2; ++sub)
#pragma unroll
        for (int nsub = 0; nsub < 4; ++nsub)
#pragma unroll
            for (int rr = 0; rr < 4; ++rr) {
                int row = bm + wave * 32 + sub * 16 + lg * 4 + rr;
                C[(size_t)row * 512 + bn + nsub * 16 + lr] = acc[sub][nsub][rr];
            }
}

// ---------------------------------------------------------------------------
// cvt_hilo: X fp32 [8192][512] -> Xh, Xl bf16 head-major [(b*8+h)*2048 + s][64]
// ---------------------------------------------------------------------------
__global__ __launch_bounds__(256) void cvt_hilo(const float* __restrict__ X,
                                                short* __restrict__ Xh,
                                                short* __restrict__ Xl) {
    int idx = blockIdx.x * 256 + threadIdx.x;   // 8192*64 total
    int r = idx >> 6;          // row (b*2048+s)
    int g = idx & 63;          // 8-float group
    int b = r >> 11, s = r & 2047;
    int h = g >> 3, dk0 = (g & 7) * 8;
    const float* src = X + (size_t)r * 512 + g * 8;
    float4 v0 = *reinterpret_cast<const float4*>(src);
    float4 v1 = *reinterpret_cast<const float4*>(src + 4);
    float f[8] = {v0.x, v0.y, v0.z, v0.w, v1.x, v1.y, v1.z, v1.w};
    short hh[8], ll[8];
#pragma unroll
    for (int e = 0; e < 8; ++e) {
        unsigned short hb = f2bf(f[e]);
        hh[e] = (short)hb;
        ll[e] = (short)f2bf(f[e] - bf2f(hb));
    }
    size_t out = ((size_t)((b * 8 + h) * 2048 + s)) * 64 + dk0;
    *(bf16x4*)(Xh + out)     = (bf16x4){hh[0], hh[1], hh[2], hh[3]};
    *(bf16x4*)(Xh + out + 4) = (bf16x4){hh[4], hh[5], hh[6], hh[7]};
    *(bf16x4*)(Xl + out)     = (bf16x4){ll[0], ll[1], ll[2], ll[3]};
    *(bf16x4*)(Xl + out + 4) = (bf16x4){ll[4], ll[5], ll[6], ll[7]};
}

// ---------------------------------------------------------------------------
// vt_kernel: V fp32 [B,S,D] -> Vt bf16 [(b*8+h)*64 + dk][2048]  (V transposed)
// ---------------------------------------------------------------------------
__global__ __launch_bounds__(256) void vt_kernel(const float* __restrict__ V,
                                                 short* __restrict__ Vt) {
    __shared__ short tile[64][72];
    const int bh = blockIdx.y;
    const int b = bh >> 3, h = bh & 7;
    const int j0 = blockIdx.x * 64;
    const int tid = threadIdx.x;
    {
        int jj = tid >> 2;
        int c = (tid & 3) * 16;
        const float* src = V + ((size_t)(b * 2048 + j0 + jj)) * 512 + h * 64 + c;
#pragma unroll
        for (int q = 0; q < 4; ++q) {
            float4 v = *reinterpret_cast<const float4*>(src + q * 4);
            tile[jj][c + q * 4 + 0] = (short)f2bf(v.x);
            tile[jj][c + q * 4 + 1] = (short)f2bf(v.y);
            tile[jj][c + q * 4 + 2] = (short)f2bf(v.z);
            tile[jj][c + q * 4 + 3] = (short)f2bf(v.w);
        }
    }
    __syncthreads();
    {
        int dk = tid >> 2;
        int jq = (tid & 3) * 16;
        short* dst = Vt + ((size_t)(bh * 64 + dk)) * 2048 + j0 + jq;
#pragma unroll
        for (int q = 0; q < 4; ++q) {
            bf16x4 o = {tile[jq + q * 4 + 0][dk], tile[jq + q * 4 + 1][dk],
                        tile[jq + q * 4 + 2][dk], tile[jq + q * 4 + 3][dk]};
            *(bf16x4*)(dst + q * 4) = o;
        }
    }
}

// ---------------------------------------------------------------------------
// mask_pack: mask int32 [B,1,S,S] -> pk u64 [b*2048+i][32], bit jl = mask!=0
// ---------------------------------------------------------------------------
__global__ __launch_bounds__(256) void mask_pack(const int* __restrict__ mask,
                                                 unsigned long long* __restrict__ pk) {
    const int row = blockIdx.x;               // b*2048 + i
    const int tid = threadIdx.x;
    const int* mrow = mask + (size_t)row * 2048;
#pragma unroll
    for (int p = 0; p < 8; ++p) {
        int j = p * 256 + tid;
        unsigned long long bal = __ballot(mrow[j] != 0);
        if ((tid & 63) == 0) pk[(size_t)row * 32 + p * 4 + (tid >> 6)] = bal;
    }
}

// ---------------------------------------------------------------------------
// Fused attention v2 (unchanged from round 6): pre-converted bf16 inputs,
// packed mask, 1 barrier/iter. Grid (32 i-tiles, 32 bh), 256 thr = 4 waves.
// ---------------------------------------------------------------------------
__global__ __launch_bounds__(256, 3) void fused_attn(
    const short* __restrict__ Qh_g, const short* __restrict__ Ql_g,
    const short* __restrict__ Kh_g, const short* __restrict__ Kl_g,
    const short* __restrict__ Vt_g, const unsigned long long* __restrict__ pk,
    float* __restrict__ P, float* __restrict__ Ag) {
    __shared__ __align__(16) short Kbuf[2][2][4096];  // [dbuf][hi/lo][64*64], XOR-swz
    __shared__ __align__(16) short Wt[4096];          // weights bf16 [64][64], XOR-swz

    const int tid = threadIdx.x;
    const int wave = tid >> 6;
    const int lane = tid & 63;
    const int lg = lane >> 4;
    const int lr = lane & 15;
    const int bh = blockIdx.y;
    const int b = bh >> 3;
    const int i0 = blockIdx.x * 64;

    // Q fragments direct from global (head-major, plain layout)
    bf16x8 qh[2], ql[2];
    {
        const size_t qbase = ((size_t)bh * 2048 + i0 + wave * 16 + lr) * 64;
#pragma unroll
        for (int ks = 0; ks < 2; ++ks) {
            qh[ks] = *(const bf16x8*)(Qh_g + qbase + (ks * 4 + lg) * 8);
            ql[ks] = *(const bf16x8*)(Ql_g + qbase + (ks * 4 + lg) * 8);
        }
    }

    // staging offsets: thread copies 2x16B per 8KB tile (linear global, swz LDS)
    const int o0 = tid * 16;
    const int o1 = 4096 + tid * 16;
    const int s0 = o0 ^ (((o0 >> 7) & 7) << 4);
    const int s1 = o1 ^ (((o1 >> 7) & 7) << 4);

    bf16x8 Rh0, Rh1, Rl0, Rl1;
#define LOADK(t)                                                            \
    {                                                                       \
        const short* bKh = Kh_g + ((size_t)bh * 2048 + (t) * 64) * 64;      \
        const short* bKl = Kl_g + ((size_t)bh * 2048 + (t) * 64) * 64;      \
        Rh0 = *(const bf16x8*)(bKh + (o0 >> 1));                            \
        Rh1 = *(const bf16x8*)(bKh + (o1 >> 1));                            \
        Rl0 = *(const bf16x8*)(bKl + (o0 >> 1));                            \
        Rl1 = *(const bf16x8*)(bKl + (o1 >> 1));                            \
    }
#define WRITEK(cur)                                                         \
    {                                                                       \
        *(bf16x8*)(&Kbuf[cur][0][0] + (s0 >> 1)) = Rh0;                     \
        *(bf16x8*)(&Kbuf[cur][0][0] + (s1 >> 1)) = Rh1;                     \
        *(bf16x8*)(&Kbuf[cur][1][0] + (s0 >> 1)) = Rl0;                     \
        *(bf16x8*)(&Kbuf[cur][1][0] + (s1 >> 1)) = Rl1;                     \
    }

    const int gi_row = i0 + wave * 16 + lg * 4;     // + rr
    const size_t pkrow = (size_t)b * 2048 + gi_row; // + rr

    // ========================= sweep 1: row stats =========================
    float m_[4] = {-1e30f, -1e30f, -1e30f, -1e30f};
    float l_[4] = {0.f, 0.f, 0.f, 0.f};

    LOADK(0);
    for (int t = 0; t < 32; ++t) {
        const int cur = t & 1;
        WRITEK(cur);
        if (t < 31) LOADK(t + 1);
        unsigned long long pkv[4];
#pragma unroll
        for (int rr = 0; rr < 4; ++rr) pkv[rr] = pk[(pkrow + rr) * 32 + t];
        __syncthreads();

        const short* KH = &Kbuf[cur][0][0];
        const short* KL = &Kbuf[cur][1][0];
        float sv[4][4];
#pragma unroll
        for (int jt = 0; jt < 4; ++jt) {
            f32x4 s = (f32x4){0.f, 0.f, 0.f, 0.f};
            int r = jt * 16 + lr;
#pragma unroll
            for (int ks = 0; ks < 2; ++ks) {
                int off = (r * 128 + (ks * 4 + lg) * 16) ^ ((r & 7) << 4);
                bf16x8 kh = *(const bf16x8*)(KH + (off >> 1));
                bf16x8 kl = *(const bf16x8*)(KL + (off >> 1));
                s = MFMA32(qh[ks], kh, s);
                s = MFMA32(qh[ks], kl, s);
                s = MFMA32(ql[ks], kh, s);
            }
#pragma unroll
            for (int rr = 0; rr < 4; ++rr) {
                bool mk = (pkv[rr] >> (jt * 16 + lr)) & 1ull;
                sv[jt][rr] = mk ? -1e30f : s[rr] * 0.125f;
            }
        }
#pragma unroll
        for (int rr = 0; rr < 4; ++rr) {
            float tm = fmaxf(fmaxf(sv[0][rr], sv[1][rr]), fmaxf(sv[2][rr], sv[3][rr]));
            tm = fmaxf(tm, __shfl_xor(tm, 1));
            tm = fmaxf(tm, __shfl_xor(tm, 2));
            tm = fmaxf(tm, __shfl_xor(tm, 4));
            tm = fmaxf(tm, __shfl_xor(tm, 8));
            float nm = fmaxf(m_[rr], tm);
            float fac = __expf(m_[rr] - nm);
            float ts = 0.f;
#pragma unroll
            for (int jt = 0; jt < 4; ++jt)
                ts += (sv[jt][rr] > -1e29f) ? __expf(sv[jt][rr] - nm) : 0.f;
            ts += __shfl_xor(ts, 1);
            ts += __shfl_xor(ts, 2);
            ts += __shfl_xor(ts, 4);
            ts += __shfl_xor(ts, 8);
            l_[rr] = l_[rr] * fac + ts;
            m_[rr] = nm;
        }
    }

    float invl[4];
#pragma unroll
    for (int rr = 0; rr < 4; ++rr) invl[rr] = 1.0f / fmaxf(l_[rr], 1e-37f);

    // ====================== sweep 2: weights + P + PV ======================
    f32x4 Oa[4];
#pragma unroll
    for (int dt = 0; dt < 4; ++dt) Oa[dt] = (f32x4){0.f, 0.f, 0.f, 0.f};

    LOADK(0);
    for (int t = 0; t < 32; ++t) {
        const int cur = t & 1;
        WRITEK(cur);
        if (t < 31) LOADK(t + 1);
        unsigned long long pkv[4];
#pragma unroll
        for (int rr = 0; rr < 4; ++rr) pkv[rr] = pk[(pkrow + rr) * 32 + t];
        // V fragments for this tile, direct from global (consumed at iter end)
        bf16x8 vf[4][2];
#pragma unroll
        for (int dt = 0; dt < 4; ++dt)
#pragma unroll
            for (int ks2 = 0; ks2 < 2; ++ks2)
                vf[dt][ks2] = *(const bf16x8*)(Vt_g +
                    ((size_t)(bh * 64 + dt * 16 + lr)) * 2048 + t * 64 + (ks2 * 4 + lg) * 8);
        __syncthreads();

        const short* KH = &Kbuf[cur][0][0];
        const short* KL = &Kbuf[cur][1][0];
        // scores -> normalized weights (bf16) into Wt (wave-private rows)
#pragma unroll
        for (int jt = 0; jt < 4; ++jt) {
            f32x4 s = (f32x4){0.f, 0.f, 0.f, 0.f};
            int r = jt * 16 + lr;
#pragma unroll
            for (int ks = 0; ks < 2; ++ks) {
                int off = (r * 128 + (ks * 4 + lg) * 16) ^ ((r & 7) << 4);
                bf16x8 kh = *(const bf16x8*)(KH + (off >> 1));
                bf16x8 kl = *(const bf16x8*)(KL + (off >> 1));
                s = MFMA32(qh[ks], kh, s);
                s = MFMA32(qh[ks], kl, s);
                s = MFMA32(ql[ks], kh, s);
            }
#pragma unroll
            for (int rr = 0; rr < 4; ++rr) {
                bool mk = (pkv[rr] >> (jt * 16 + lr)) & 1ull;
                float w = mk ? 0.f : __expf(s[rr] * 0.125f - m_[rr]) * invl[rr];
                int rw = wave * 16 + lg * 4 + rr;
                int wo = rw * 64 + (((jt * 2 + (lr >> 3)) ^ (rw & 7)) << 3) + (lr & 7);
                Wt[wo] = (short)f2bf(w);
            }
        }

        // P write (wave-own rows): bf16 Wt -> fp32, fully coalesced 16B stores
        {
            int rp = wave * 16 + (lane >> 2);
            int c2 = (lane & 3) * 2;
            int po0 = rp * 64 + (((c2 + 0) ^ (rp & 7)) << 3);
            int po1 = rp * 64 + (((c2 + 1) ^ (rp & 7)) << 3);
            bf16x8 wa = *(const bf16x8*)(Wt + po0);
            bf16x8 wb = *(const bf16x8*)(Wt + po1);
            float* Prow = P + ((size_t)bh * 2048 + i0 + rp) * 2048 + t * 64 + (lane & 3) * 16;
#pragma unroll
            for (int q = 0; q < 2; ++q) {
                f32x4 oA = {bf2f((unsigned short)wa[q * 4 + 0]), bf2f((unsigned short)wa[q * 4 + 1]),
                            bf2f((unsigned short)wa[q * 4 + 2]), bf2f((unsigned short)wa[q * 4 + 3])};
                f32x4 oB = {bf2f((unsigned short)wb[q * 4 + 0]), bf2f((unsigned short)wb[q * 4 + 1]),
                            bf2f((unsigned short)wb[q * 4 + 2]), bf2f((unsigned short)wb[q * 4 + 3])};
                *(f32x4*)(Prow + q * 4) = oA;
                *(f32x4*)(Prow + 8 + q * 4) = oB;
            }
        }

        // PV: A-frag = wave's own Wt rows, B-frag = V^T from registers
        bf16x8 aw[2];
#pragma unroll
        for (int ks2 = 0; ks2 < 2; ++ks2) {
            int ra = wave * 16 + lr;
            int ao = ra * 64 + (((ks2 * 4 + lg) ^ (ra & 7)) << 3);
            aw[ks2] = *(const bf16x8*)(Wt + ao);
        }
#pragma unroll
        for (int dt = 0; dt < 4; ++dt)
#pragma unroll
            for (int ks2 = 0; ks2 < 2; ++ks2)
                Oa[dt] = MFMA32(aw[ks2], vf[dt][ks2], Oa[dt]);
    }

    // context (pre-W_o) out
    {
        const int h = bh & 7;
        float* Ab = Ag + ((size_t)(b * S_)) * D_ + h * DK_;
#pragma unroll
        for (int dt = 0; dt < 4; ++dt)
#pragma unroll
            for (int rr = 0; rr < 4; ++rr) {
                int gi = i0 + wave * 16 + lg * 4 + rr;
                Ab[(size_t)gi * D_ + dt * 16 + lr] = Oa[dt][rr];
            }
    }
#undef LOADK
#undef WRITEK
}

// ---------------------------------------------------------------------------
extern "C" void kernel_launch(void* const* d_in, const int* in_sizes, int n_in,
                              void* d_out, int out_size, void* d_ws, size_t ws_size,
                              hipStream_t stream) {
    const float* q   = (const float*)d_in[0];
    const float* k   = (const float*)d_in[1];
    const float* v   = (const float*)d_in[2];
    const int*   msk = (const int*)d_in[3];
    const float* w_q = (const float*)d_in[4];
    const float* w_k = (const float*)d_in[5];
    const float* w_v = (const float*)d_in[6];
    const float* w_o = (const float*)d_in[7];

    float* out = (float*)d_out;                 // [B,S,D]
    float* P   = out + (size_t)B_ * S_ * D_;    // [B,H,S,S]

    float* ws = (float*)d_ws;
    float* Qf = ws;                             // [8192][512] fp32
    float* Kf = Qf + (size_t)M_ * D_;
    float* Vf = Kf + (size_t)M_ * D_;
    short* S0 = (short*)(Vf + (size_t)M_ * D_);
    short* Qh = S0;                             // [32][2048][64] bf16 head-major
    short* Ql = Qh + (size_t)4194304;
    short* Kh = Ql + (size_t)4194304;
    short* Kl = Kh + (size_t)4194304;
    short* Vt = Kl + (size_t)4194304;           // [32][64][2048] bf16 (V^T)
    unsigned long long* pk = (unsigned long long*)(Vt + (size_t)4194304);
    float* A = Qf;                              // context aliases Qf (safe: Qf only read by cvt)

    dim3 blk(256);
    dim3 gproj(M_ / 128, D_ / 64);              // (64, 8)

    hipLaunchKernelGGL(gemm_nt_mfma, gproj, blk, 0, stream, q, w_q, Qf);
    hipLaunchKernelGGL(gemm_nt_mfma, gproj, blk, 0, stream, k, w_k, Kf);
    hipLaunchKernelGGL(gemm_nt_mfma, gproj, blk, 0, stream, v, w_v, Vf);

    hipLaunchKernelGGL(cvt_hilo, dim3(2048), blk, 0, stream, Qf, Qh, Ql);
    hipLaunchKernelGGL(cvt_hilo, dim3(2048), blk, 0, stream, Kf, Kh, Kl);
    hipLaunchKernelGGL(vt_kernel, dim3(32, 32), blk, 0, stream, Vf, Vt);
    hipLaunchKernelGGL(mask_pack, dim3(M_), blk, 0, stream, msk, pk);

    hipLaunchKernelGGL(fused_attn, dim3(32, 32), blk, 0, stream,
                       Qh, Ql, Kh, Kl, Vt, pk, P, A);

    hipLaunchKernelGGL(gemm_nt_mfma, gproj, blk, 0, stream, A, w_o, out);
}